// Round 12
// baseline (256.018 us; speedup 1.0000x reference)
//
#include <hip/hip_runtime.h>

// Part_Graph GNN forward on MI355X.
// Inputs: FLOAT32. Output: FLOAT32 (concat):
// [0] xp_new (16,60,3600) | [1] pu_map (16,5,3600) | [2] pl_map (16,3,3600)
// | [3] att_raw (16,16,3600) | [4] ctx_att (16,12,3600)

#define P_TOT 57600
#define RSQEPS 0.99999500003749969f
#define O2 3456000
#define O3 3744000
#define O4 3916800
#define O5 4838400

typedef __attribute__((ext_vector_type(8))) short s8v;
typedef __attribute__((ext_vector_type(4))) short s4v;
typedef __attribute__((ext_vector_type(4))) float f4v;

__device__ __forceinline__ float bf2f(short s) {
  union { unsigned int i; float f; } u;
  u.i = ((unsigned int)(unsigned short)s) << 16;
  return u.f;
}
__device__ __forceinline__ short f2bf(float f) {
  union { float f; unsigned int i; } u; u.f = f;
  unsigned int r = (u.i + 0x7FFFu + ((u.i >> 16) & 1u)) >> 16;
  return (short)r;
}

// LDS tile index with bank swizzle (same formula for reader and writer).
// XOR of multiples of 8 preserves 4- and 8-element alignment (b64/b128 ok).
__device__ __forceinline__ int swz(int m, int c) {
  return m * 256 + (c ^ ((((m >> 3) ^ m) & 7) << 3));
}

// Anti-hoist fence: stops the scheduler lifting weight ds_reads across matmul
// rows (k4 rounds 4/7 spilled to 256 VGPR + ~500 MB scratch without this).
__device__ __forceinline__ void fence() {
  asm volatile("" ::: "memory");
  __builtin_amdgcn_sched_barrier(0);
}

// ---------------- K0: MFMA-order weight packing (f32 -> bf16) --------------
#define NW1U 49152
#define NUW  55296
__global__ __launch_bounds__(256) void k0_prep(
    const float* __restrict__ w1, const float* __restrict__ w2,
    short* __restrict__ w1p, short* __restrict__ w2p) {
  int i = blockIdx.x * 256 + threadIdx.x;
  if (i < NW1U) {
    int g = i;
    int lane = g & 63, t1 = g >> 6;
    int kk = t1 & 7, t2 = t1 >> 3;
    int ni = t2 & 3, t3 = t2 >> 2;
    int nblk = t3 & 3, head = t3 >> 2;
    int o = nblk * 64 + ni * 16 + (lane & 15);
    const float* src = w1 + (size_t)head * 65536 + (size_t)o * 256 + kk * 32 + (lane >> 4) * 8;
    short* d = w1p + (size_t)g * 8;
#pragma unroll
    for (int j = 0; j < 8; ++j) d[j] = f2bf(src[j]);
  } else {
    int g = i - NW1U;
    int lane = g & 63, t1 = g >> 6;
    int kk = t1 & 7, t2 = t1 >> 3;
    int f = t2 & 1, head = t2 >> 1;
    int row = f * 16 + (lane & 15);
    short* d = w2p + (size_t)g * 8;
    if (row < 20) {
      const float* src = w2 + (size_t)head * 5120 + (size_t)row * 256 + kk * 32 + (lane >> 4) * 8;
#pragma unroll
      for (int j = 0; j < 8; ++j) d[j] = f2bf(src[j]);
    } else {
#pragma unroll
      for (int j = 0; j < 8; ++j) d[j] = 0;
    }
  }
}

// ---------------- K1: fused proj1 + proj2, transposed GEMMs ----------------
// D = W·X^T. aW loads 2-deep register ping-pong prefetched (L2-latency fix).
__global__ __launch_bounds__(256, 3) void k1_proj(
    const float* __restrict__ xp, const short* __restrict__ w1p,
    const float* __restrict__ g1, const float* __restrict__ b1,
    const short* __restrict__ w2p,
    const float* __restrict__ g2, const float* __restrict__ b2,
    short* __restrict__ ctx) {
  __shared__ __align__(16) short sA[48 * 256];
  __shared__ __align__(16) short sH[48 * 256];
  const int t = threadIdx.x;
  const int p0 = blockIdx.x * 48;         // 48 | 3600 -> never crosses an image
  const int n = p0 / 3600;
  const int hw0 = p0 % 3600;
  const int lane = t & 63;
  const int wid = t >> 6;
  const int l15 = lane & 15;
  const int lg = lane >> 4;

  // stage xp tile (f32 -> bf16): unit u -> (m0=(u%6)*8, c=u/6)
  const float* xpn = xp + (size_t)n * 256 * 3600 + hw0;
#pragma unroll
  for (int it = 0; it < 6; ++it) {
    int u = it * 256 + t;
    int q = u % 6;
    int c = u / 6;
    int m0 = q * 8;
    const float* src = xpn + c * 3600 + m0;
    f4v v0 = *((const f4v*)src);
    f4v v1 = *((const f4v*)(src + 4));
#pragma unroll
    for (int j = 0; j < 4; ++j) {
      sA[swz(m0 + j, c)] = f2bf(v0[j]);
      sA[swz(m0 + 4 + j, c)] = f2bf(v1[j]);
    }
  }
  __syncthreads();

  for (int head = 0; head < 6; ++head) {
    f4v acc[4][3];
#pragma unroll
    for (int mi = 0; mi < 4; ++mi)
#pragma unroll
      for (int nf = 0; nf < 3; ++nf) acc[mi][nf] = (f4v){0.f, 0.f, 0.f, 0.f};
    const int n0 = wid * 64;
    const short* wb = w1p + (size_t)(head * 4 + wid) * (4 * 8 * 64 * 8);
    s8v aWa[4], aWb[4];
#pragma unroll
    for (int mi = 0; mi < 4; ++mi)
      aWa[mi] = *((const s8v*)(wb + ((mi * 8 + 0) * 64 + lane) * 8));
#pragma unroll
    for (int kk = 0; kk < 8; ++kk) {
      s8v (&cur)[4] = (kk & 1) ? aWb : aWa;
      s8v (&nxt)[4] = (kk & 1) ? aWa : aWb;
      if (kk < 7) {
#pragma unroll
        for (int mi = 0; mi < 4; ++mi)
          nxt[mi] = *((const s8v*)(wb + ((mi * 8 + kk + 1) * 64 + lane) * 8));
      }
      s8v bP[3];
#pragma unroll
      for (int nf = 0; nf < 3; ++nf)
        bP[nf] = *((const s8v*)&sA[swz(nf * 16 + l15, kk * 32 + lg * 8)]);
#pragma unroll
      for (int mi = 0; mi < 4; ++mi)
#pragma unroll
        for (int nf = 0; nf < 3; ++nf)
          acc[mi][nf] = __builtin_amdgcn_mfma_f32_16x16x32_bf16(cur[mi], bP[nf], acc[mi][nf], 0, 0, 0);
    }
    // bn + relu -> sH. D: row = out-ch = n0+mi*16+lg*4+r, col = pixel = nf*16+l15.
#pragma unroll
    for (int mi = 0; mi < 4; ++mi) {
      int o4 = n0 + mi * 16 + lg * 4;      // 4 consecutive out-channels
      f4v s4 = *((const f4v*)(g1 + head * 256 + o4));
      f4v c4 = *((const f4v*)(b1 + head * 256 + o4));
#pragma unroll
      for (int nf = 0; nf < 3; ++nf) {
        int pix = nf * 16 + l15;
        s4v pk;
#pragma unroll
        for (int r = 0; r < 4; ++r)
          pk[r] = f2bf(fmaxf(acc[mi][nf][r] * (s4[r] * RSQEPS) + c4[r], 0.f));
        *((s4v*)&sH[swz(pix, o4)]) = pk;   // one ds_write_b64
      }
    }
    __syncthreads();
    if (wid < 3) {  // GEMM2 (transposed): wave w owns pixel-frag w
      f4v a20 = {0.f, 0.f, 0.f, 0.f}, a21 = {0.f, 0.f, 0.f, 0.f};
#pragma unroll
      for (int kk = 0; kk < 8; ++kk) {
        s8v bH = *((const s8v*)&sH[swz(wid * 16 + l15, kk * 32 + lg * 8)]);
        s8v w20 = *((const s8v*)(w2p + ((size_t)(((head * 2 + 0) * 8 + kk) * 64 + lane)) * 8));
        s8v w21 = *((const s8v*)(w2p + ((size_t)(((head * 2 + 1) * 8 + kk) * 64 + lane)) * 8));
        a20 = __builtin_amdgcn_mfma_f32_16x16x32_bf16(w20, bH, a20, 0, 0, 0);
        a21 = __builtin_amdgcn_mfma_f32_16x16x32_bf16(w21, bH, a21, 0, 0, 0);
      }
      // D: row = out2-ch = mf*16+lg*4+r (valid <20), col = pixel = wid*16+l15
#pragma unroll
      for (int mf = 0; mf < 2; ++mf) {
        int ch4 = mf * 16 + lg * 4;
        if (ch4 < 20) {                    // mf=1: only lg==0 (ch 16..19)
          f4v s4 = *((const f4v*)(g2 + head * 20 + ch4));
          f4v c4 = *((const f4v*)(b2 + head * 20 + ch4));
          f4v& aa = mf ? a21 : a20;
#pragma unroll
          for (int r = 0; r < 4; ++r) {
            float v = fmaxf(aa[r] * (s4[r] * RSQEPS) + c4[r], 0.f);
            ctx[(size_t)(head * 20 + ch4 + r) * P_TOT + p0 + wid * 16 + l15] = f2bf(v);
          }
        }
      }
    }
    __syncthreads();
  }
}

// ---------------- K2: att_raw / att_soft / ctx_att, one head per block.y ---
__global__ __launch_bounds__(256) void k2_att(
    const short* __restrict__ ctx,
    const float* __restrict__ attw, const float* __restrict__ attb,
    const float* __restrict__ ctxw, const float* __restrict__ ctxb,
    float* __restrict__ ws_att, float* __restrict__ out) {
  int p = blockIdx.x * 256 + threadIdx.x;
  const int i = blockIdx.y;
  int n = p / 3600, hw = p % 3600;
  const int att_off[6] = {0, 2, 5, 8, 11, 14};
  float fd[10], c0[10];
#pragma unroll
  for (int c = 0; c < 10; ++c) {
    c0[c] = bf2f(ctx[(size_t)(i * 20 + c) * P_TOT + p]);
    fd[c] = bf2f(ctx[(size_t)(i * 20 + 10 + c) * P_TOT + p]);
  }
  const int ci = (i == 0 || i == 5) ? 2 : 3;
  float a[3];
#pragma unroll
  for (int j = 0; j < 3; ++j) {
    if (j < ci) {
      float s = attb[i * 3 + j];
#pragma unroll
      for (int c = 0; c < 10; ++c) s += attw[(i * 3 + j) * 10 + c] * fd[c];
      a[j] = s;
      out[O4 + ((size_t)n * 16 + att_off[i] + j) * 3600 + hw] = s;
    }
  }
  float mx = fmaxf(a[0], a[1]);
  if (ci == 3) mx = fmaxf(mx, a[2]);
  float se = 0.f;
#pragma unroll
  for (int j = 0; j < 3; ++j)
    if (j < ci) { a[j] = __expf(a[j] - mx); se += a[j]; }
  float inv = 1.f / se;
#pragma unroll
  for (int j = 0; j < 3; ++j)
    if (j < ci) ws_att[(size_t)(i * 3 + j) * P_TOT + p] = a[j] * inv;
  float o0 = ctxb[i * 2 + 0];
  float o1 = ctxb[i * 2 + 1];
#pragma unroll
  for (int c = 0; c < 10; ++c) {
    o0 += ctxw[(i * 2 + 0) * 10 + c] * c0[c];
    o1 += ctxw[(i * 2 + 1) * 10 + c] * fd[c];
  }
  out[O5 + ((size_t)n * 12 + i * 2 + 0) * 3600 + hw] = o0;
  out[O5 + ((size_t)n * 12 + i * 2 + 1) * 3600 + hw] = o1;
}

// ---------------- K3: pu/pl maps + softmax gates (split by block.y) --------
__global__ __launch_bounds__(256) void k3_gates(
    const float* __restrict__ xh0, const float* __restrict__ xh1,
    const float* __restrict__ duw, const float* __restrict__ dub,
    const float* __restrict__ dlw, const float* __restrict__ dlb,
    float* __restrict__ ws_pu, float* __restrict__ ws_pl, float* __restrict__ out) {
  int p = blockIdx.x * 256 + threadIdx.x;
  int n = p / 3600, hw = p % 3600;
  if (blockIdx.y == 0) {
    float h[10];
#pragma unroll
    for (int c = 0; c < 10; ++c) h[c] = xh0[((size_t)n * 10 + c) * 3600 + hw];
    float a[5];
#pragma unroll
    for (int j = 0; j < 5; ++j) {
      float s = dub[j];
#pragma unroll
      for (int c = 0; c < 10; ++c) s += duw[j * 10 + c] * h[c];
      a[j] = s;
      out[O2 + ((size_t)n * 5 + j) * 3600 + hw] = s;
    }
    float mx = a[0];
#pragma unroll
    for (int j = 1; j < 5; ++j) mx = fmaxf(mx, a[j]);
    float se = 0.f;
#pragma unroll
    for (int j = 0; j < 5; ++j) { a[j] = __expf(a[j] - mx); se += a[j]; }
    float inv = 1.f / se;
#pragma unroll
    for (int j = 0; j < 5; ++j) ws_pu[(size_t)j * P_TOT + p] = a[j] * inv;
  } else {
    float h[10];
#pragma unroll
    for (int c = 0; c < 10; ++c) h[c] = xh1[((size_t)n * 10 + c) * 3600 + hw];
    float b3[3];
#pragma unroll
    for (int j = 0; j < 3; ++j) {
      float s = dlb[j];
#pragma unroll
      for (int c = 0; c < 10; ++c) s += dlw[j * 10 + c] * h[c];
      b3[j] = s;
      out[O3 + ((size_t)n * 3 + j) * 3600 + hw] = s;
    }
    float mx = fmaxf(fmaxf(b3[0], b3[1]), b3[2]);
    float se = 0.f;
#pragma unroll
    for (int j = 0; j < 3; ++j) { b3[j] = __expf(b3[j] - mx); se += b3[j]; }
    float inv = 1.f / se;
#pragma unroll
    for (int j = 0; j < 3; ++j) ws_pl[(size_t)j * P_TOT + p] = b3[j] * inv;
  }
}

// ---------------- K4: decoder + edge + GRU, TWO pixels per thread ----------
// k4 is DS-throughput-bound (round-11: ~600 uniform ds_read_b128 per wave per
// 64 pixels ≈ 63 µs of DS-pipe). Each thread now processes pixels p and p+256:
// every LDS weight row feeds both pixels' fmacs -> DS instruction count halves.
static __device__ const int INC_N[6] = {1, 2, 2, 2, 2, 1};
static __device__ const int INC_U[6][2] = {{1, 0}, {0, 2}, {1, 3}, {2, 4}, {3, 5}, {4, 0}};
static __device__ const int INC_K[6][2] = {{1, 0}, {1, 1}, {2, 1}, {2, 1}, {2, 1}, {2, 0}};

// LDS layout (floats): 0: c1w[3][400] | 1200: c1s[3][20] | 1260: c1b[3][20]
// | 1320: c2w[3][200] | 1920: c2s[3][10] | 1950: c2b[3][10]
// | 1980: gw[400] | 2380: gb[20] | 2400: cw[200] | 2600: cb[10]  (2610 total)
template <bool ACCUM>
__device__ __forceinline__ void block2_l2(
    const float* __restrict__ w1, const float* __restrict__ s1, const float* __restrict__ b1,
    const float* __restrict__ w2, const float* __restrict__ s2, const float* __restrict__ b2,
    const float* __restrict__ inaA, const float* __restrict__ inbA,
    const float* __restrict__ inaB, const float* __restrict__ inbB,
    float* __restrict__ outA, float* __restrict__ outB) {
  float hA[20], hB[20];
#pragma unroll
  for (int o = 0; o < 20; ++o) {
    float aA = 0.f, aB = 0.f;
#pragma unroll
    for (int c = 0; c < 10; ++c) {
      float wlo = w1[o * 20 + c], whi = w1[o * 20 + 10 + c];
      aA += wlo * inaA[c] + whi * inbA[c];
      aB += wlo * inaB[c] + whi * inbB[c];
    }
    float ss = s1[o], bb = b1[o];
    hA[o] = fmaxf(aA * ss + bb, 0.f);
    hB[o] = fmaxf(aB * ss + bb, 0.f);
    if ((o & 3) == 3) fence();
  }
#pragma unroll
  for (int o = 0; o < 10; ++o) {
    float aA = 0.f, aB = 0.f;
#pragma unroll
    for (int c = 0; c < 20; ++c) {
      float w = w2[o * 20 + c];
      aA += w * hA[c];
      aB += w * hB[c];
    }
    float ss = s2[o], bb = b2[o];
    float vA = fmaxf(aA * ss + bb, 0.f);
    float vB = fmaxf(aB * ss + bb, 0.f);
    if (ACCUM) { outA[o] += vA; outB[o] += vB; }
    else       { outA[o] = vA;  outB[o] = vB; }
    if ((o & 3) == 3) fence();
  }
  fence();
}

__global__ __launch_bounds__(256) void k4_node(
    const float* __restrict__ xh0, const float* __restrict__ xh1,
    const float* __restrict__ xp0, const float* __restrict__ xp1,
    const float* __restrict__ xp2, const float* __restrict__ xp3,
    const float* __restrict__ xp4, const float* __restrict__ xp5,
    const float* __restrict__ ws_pu, const float* __restrict__ ws_pl,
    const float* __restrict__ ws_att, const short* __restrict__ ctx,
    const float* __restrict__ c1wg, const float* __restrict__ c1gg, const float* __restrict__ c1bg,
    const float* __restrict__ c2wg, const float* __restrict__ c2gg, const float* __restrict__ c2bg,
    const float* __restrict__ gwg, const float* __restrict__ gbg,
    const float* __restrict__ cwg, const float* __restrict__ cbg,
    float* __restrict__ out) {
  __shared__ float W[2610];
  const int t = threadIdx.x;
  const int node = blockIdx.y;
  for (int u = t; u < 2610; u += 256) {
    float v;
    if (u < 1200) v = c1wg[u];
    else if (u < 1260) v = c1gg[u - 1200] * RSQEPS;
    else if (u < 1320) v = c1bg[u - 1260];
    else if (u < 1920) v = c2wg[u - 1320];
    else if (u < 1950) v = c2gg[u - 1920] * RSQEPS;
    else if (u < 1980) v = c2bg[u - 1950];
    else if (u < 2380) v = gwg[node * 400 + (u - 1980)];
    else if (u < 2400) v = gbg[node * 20 + (u - 2380)];
    else if (u < 2600) v = cwg[node * 200 + (u - 2400)];
    else v = cbg[node * 10 + (u - 2600)];
    W[u] = v;
  }
  __syncthreads();
  const int sdec = (node < 4) ? 0 : 1;
  const int pA = blockIdx.x * 512 + t;
  const int pBr = pA + 256;
  const bool vB = pBr < P_TOT;
  const int pB = vB ? pBr : P_TOT - 1;      // clamp loads; stores guarded
  const int nA = pA / 3600, hwA = pA % 3600;
  const int nB = pB / 3600, hwB = pB % 3600;
  const float* xhp = (node < 4) ? xh0 : xh1;
  const float* xpl = node == 0 ? xp0 : node == 1 ? xp1 : node == 2 ? xp2
                   : node == 3 ? xp3 : node == 4 ? xp4 : xp5;
  float xpiA[10], xpiB[10];
#pragma unroll
  for (int c = 0; c < 10; ++c) {
    xpiA[c] = xpl[((size_t)nA * 10 + c) * 3600 + hwA];
    xpiB[c] = xpl[((size_t)nB * 10 + c) * 3600 + hwB];
  }
  const float* gatep = (node < 4) ? ws_pu : ws_pl;
  const int gidx = (node < 4) ? node + 1 : node - 3;
  float attgA = gatep[(size_t)gidx * P_TOT + pA];
  float attgB = gatep[(size_t)gidx * P_TOT + pB];
  float gatedA[10], gatedB[10], msgA[10], msgB[10];
#pragma unroll
  for (int c = 0; c < 10; ++c) {
    gatedA[c] = xhp[((size_t)nA * 10 + c) * 3600 + hwA] * attgA;
    gatedB[c] = xhp[((size_t)nB * 10 + c) * 3600 + hwB] * attgB;
  }
  fence();
  block2_l2<false>(W + sdec * 400, W + 1200 + sdec * 20, W + 1260 + sdec * 20,
                   W + 1320 + sdec * 200, W + 1920 + sdec * 10, W + 1950 + sdec * 10,
                   gatedA, xpiA, gatedB, xpiB, msgA, msgB);
  const int ne = INC_N[node];
#pragma unroll 1
  for (int e = 0; e < ne; ++e) {
    int uu = INC_U[node][e], kk = INC_K[node][e];
    float avA = ws_att[(size_t)(uu * 3 + kk) * P_TOT + pA];
    float avB = ws_att[(size_t)(uu * 3 + kk) * P_TOT + pB];
#pragma unroll
    for (int c = 0; c < 10; ++c) {
      gatedA[c] = avA * bf2f(ctx[(size_t)(uu * 20 + 10 + c) * P_TOT + pA]);
      gatedB[c] = avB * bf2f(ctx[(size_t)(uu * 20 + 10 + c) * P_TOT + pB]);
    }
    fence();
    block2_l2<true>(W + 800, W + 1240, W + 1300, W + 1720, W + 1940, W + 1970,
                    gatedA, xpiA, gatedB, xpiB, msgA, msgB);
  }
  // GRU (dual-pixel, shared weight reads)
  float g20A[20], g20B[20];
#pragma unroll
  for (int o = 0; o < 20; ++o) {
    float aA = W[2380 + o], aB = aA;
#pragma unroll
    for (int c = 0; c < 10; ++c) {
      float wlo = W[1980 + o * 20 + c], whi = W[1980 + o * 20 + 10 + c];
      aA += wlo * msgA[c] + whi * xpiA[c];
      aB += wlo * msgB[c] + whi * xpiB[c];
    }
    g20A[o] = aA; g20B[o] = aB;
    if ((o & 3) == 3) fence();
  }
  float rhA[10], rhB[10];
#pragma unroll
  for (int c = 0; c < 10; ++c) {
    rhA[c] = xpiA[c] / (1.f + __expf(-g20A[c]));
    rhB[c] = xpiB[c] / (1.f + __expf(-g20B[c]));
  }
#pragma unroll
  for (int o = 0; o < 10; ++o) {
    float aA = W[2600 + o], aB = aA;
#pragma unroll
    for (int c = 0; c < 10; ++c) {
      float wlo = W[2400 + o * 20 + c], whi = W[2400 + o * 20 + 10 + c];
      aA += wlo * msgA[c] + whi * rhA[c];
      aB += wlo * msgB[c] + whi * rhB[c];
    }
    // tanh(x) = 1 - 2/(exp(2x)+1), inline, saturating
    float cdA = 1.f - 2.f / (__expf(2.f * aA) + 1.f);
    float cdB = 1.f - 2.f / (__expf(2.f * aB) + 1.f);
    float zA = 1.f / (1.f + __expf(-g20A[10 + o]));
    float zB = 1.f / (1.f + __expf(-g20B[10 + o]));
    out[((size_t)nA * 60 + node * 10 + o) * 3600 + hwA] = (1.f - zA) * xpiA[o] + zA * cdA;
    if (vB)
      out[((size_t)nB * 60 + node * 10 + o) * 3600 + hwB] = (1.f - zB) * xpiB[o] + zB * cdB;
    if ((o & 3) == 3) fence();
  }
}

// ---------------- launcher -------------------------------------------------
extern "C" void kernel_launch(void* const* d_in, const int* in_sizes, int n_in,
                              void* d_out, int out_size, void* d_ws, size_t ws_size,
                              hipStream_t stream) {
  const float* xh0 = (const float*)d_in[1];
  const float* xh1 = (const float*)d_in[2];
  const float* xp0 = (const float*)d_in[3];
  const float* xp1 = (const float*)d_in[4];
  const float* xp2 = (const float*)d_in[5];
  const float* xp3 = (const float*)d_in[6];
  const float* xp4 = (const float*)d_in[7];
  const float* xp5 = (const float*)d_in[8];
  const float* xp  = (const float*)d_in[9];
  const float* p1w = (const float*)d_in[10];
  const float* p1g = (const float*)d_in[11];
  const float* p1b = (const float*)d_in[12];
  const float* p2w = (const float*)d_in[13];
  const float* p2g = (const float*)d_in[14];
  const float* p2b = (const float*)d_in[15];
  const float* attw = (const float*)d_in[16];
  const float* attb = (const float*)d_in[17];
  const float* ctxw = (const float*)d_in[18];
  const float* ctxb = (const float*)d_in[19];
  const float* duw = (const float*)d_in[20];
  const float* dub = (const float*)d_in[21];
  const float* dlw = (const float*)d_in[22];
  const float* dlb = (const float*)d_in[23];
  const float* c1w = (const float*)d_in[24];
  const float* c1g = (const float*)d_in[25];
  const float* c1b = (const float*)d_in[26];
  const float* c2w = (const float*)d_in[27];
  const float* c2g = (const float*)d_in[28];
  const float* c2b = (const float*)d_in[29];
  const float* gw  = (const float*)d_in[30];
  const float* gb  = (const float*)d_in[31];
  const float* cw  = (const float*)d_in[32];
  const float* cb  = (const float*)d_in[33];

  // Workspace layout (bytes) — total 20,699,136 B (~19.7 MB):
  char* wsb = (char*)d_ws;
  short* w1p   = (short*)(wsb);              //    786,432 B
  short* w2p   = (short*)(wsb + 786432);     //     98,304 B
  short* ctxb2 = (short*)(wsb + 884736);     // 13,824,000 B (bf16 ctx [120][57600])
  float* ws_att = (float*)(wsb + 14708736);  //  4,147,200 B
  float* ws_pu  = (float*)(wsb + 18855936);  //  1,152,000 B
  float* ws_pl  = (float*)(wsb + 20007936);  //    691,200 B
  float* out = (float*)d_out;

  k0_prep<<<216, 256, 0, stream>>>(p1w, p2w, w1p, w2p);
  k1_proj<<<1200, 256, 0, stream>>>(xp, w1p, p1g, p1b, w2p, p2g, p2b, ctxb2);
  k2_att<<<dim3(225, 6), 256, 0, stream>>>(ctxb2, attw, attb, ctxw, ctxb, ws_att, out);
  k3_gates<<<dim3(225, 2), 256, 0, stream>>>(xh0, xh1, duw, dub, dlw, dlb, ws_pu, ws_pl, out);
  k4_node<<<dim3(113, 6), 256, 0, stream>>>(xh0, xh1, xp0, xp1, xp2, xp3, xp4, xp5,
      ws_pu, ws_pl, ws_att, ctxb2,
      c1w, c1g, c1b, c2w, c2g, c2b, gw, gb, cw, cb, out);
}

// Round 13
// 173.214 us; speedup vs baseline: 1.4780x; 1.4780x over previous
//
#include <hip/hip_runtime.h>

// Part_Graph GNN forward on MI355X.
// Inputs: FLOAT32. Output: FLOAT32 (concat):
// [0] xp_new (16,60,3600) | [1] pu_map (16,5,3600) | [2] pl_map (16,3,3600)
// | [3] att_raw (16,16,3600) | [4] ctx_att (16,12,3600)

#define P_TOT 57600
#define RSQEPS 0.99999500003749969f
#define O2 3456000
#define O3 3744000
#define O4 3916800
#define O5 4838400

typedef __attribute__((ext_vector_type(8))) short s8v;
typedef __attribute__((ext_vector_type(4))) short s4v;
typedef __attribute__((ext_vector_type(4))) float f4v;

__device__ __forceinline__ float bf2f(short s) {
  union { unsigned int i; float f; } u;
  u.i = ((unsigned int)(unsigned short)s) << 16;
  return u.f;
}
__device__ __forceinline__ short f2bf(float f) {
  union { float f; unsigned int i; } u; u.f = f;
  unsigned int r = (u.i + 0x7FFFu + ((u.i >> 16) & 1u)) >> 16;
  return (short)r;
}

// LDS tile index with bank swizzle (same formula for reader and writer).
// XOR of multiples of 8 preserves 4- and 8-element alignment (b64/b128 ok).
__device__ __forceinline__ int swz(int m, int c) {
  return m * 256 + (c ^ ((((m >> 3) ^ m) & 7) << 3));
}

// Anti-hoist fence: stops the scheduler lifting weight ds_reads across matmul
// rows (k4 rounds 4/7 spilled to 256 VGPR + ~500 MB scratch without this).
__device__ __forceinline__ void fence() {
  asm volatile("" ::: "memory");
  __builtin_amdgcn_sched_barrier(0);
}

// ---------------- K0: MFMA-order weight packing (f32 -> bf16) --------------
#define NW1U 49152
#define NUW  55296
__global__ __launch_bounds__(256) void k0_prep(
    const float* __restrict__ w1, const float* __restrict__ w2,
    short* __restrict__ w1p, short* __restrict__ w2p) {
  int i = blockIdx.x * 256 + threadIdx.x;
  if (i < NW1U) {
    int g = i;
    int lane = g & 63, t1 = g >> 6;
    int kk = t1 & 7, t2 = t1 >> 3;
    int ni = t2 & 3, t3 = t2 >> 2;
    int nblk = t3 & 3, head = t3 >> 2;
    int o = nblk * 64 + ni * 16 + (lane & 15);
    const float* src = w1 + (size_t)head * 65536 + (size_t)o * 256 + kk * 32 + (lane >> 4) * 8;
    short* d = w1p + (size_t)g * 8;
#pragma unroll
    for (int j = 0; j < 8; ++j) d[j] = f2bf(src[j]);
  } else {
    int g = i - NW1U;
    int lane = g & 63, t1 = g >> 6;
    int kk = t1 & 7, t2 = t1 >> 3;
    int f = t2 & 1, head = t2 >> 1;
    int row = f * 16 + (lane & 15);
    short* d = w2p + (size_t)g * 8;
    if (row < 20) {
      const float* src = w2 + (size_t)head * 5120 + (size_t)row * 256 + kk * 32 + (lane >> 4) * 8;
#pragma unroll
      for (int j = 0; j < 8; ++j) d[j] = f2bf(src[j]);
    } else {
#pragma unroll
      for (int j = 0; j < 8; ++j) d[j] = 0;
    }
  }
}

// ---------------- K1: fused proj1 + proj2, transposed GEMMs ----------------
// D = W·X^T. aW loads 2-deep register ping-pong prefetched (L2-latency fix).
__global__ __launch_bounds__(256, 3) void k1_proj(
    const float* __restrict__ xp, const short* __restrict__ w1p,
    const float* __restrict__ g1, const float* __restrict__ b1,
    const short* __restrict__ w2p,
    const float* __restrict__ g2, const float* __restrict__ b2,
    short* __restrict__ ctx) {
  __shared__ __align__(16) short sA[48 * 256];
  __shared__ __align__(16) short sH[48 * 256];
  const int t = threadIdx.x;
  const int p0 = blockIdx.x * 48;         // 48 | 3600 -> never crosses an image
  const int n = p0 / 3600;
  const int hw0 = p0 % 3600;
  const int lane = t & 63;
  const int wid = t >> 6;
  const int l15 = lane & 15;
  const int lg = lane >> 4;

  // stage xp tile (f32 -> bf16): unit u -> (m0=(u%6)*8, c=u/6)
  const float* xpn = xp + (size_t)n * 256 * 3600 + hw0;
#pragma unroll
  for (int it = 0; it < 6; ++it) {
    int u = it * 256 + t;
    int q = u % 6;
    int c = u / 6;
    int m0 = q * 8;
    const float* src = xpn + c * 3600 + m0;
    f4v v0 = *((const f4v*)src);
    f4v v1 = *((const f4v*)(src + 4));
#pragma unroll
    for (int j = 0; j < 4; ++j) {
      sA[swz(m0 + j, c)] = f2bf(v0[j]);
      sA[swz(m0 + 4 + j, c)] = f2bf(v1[j]);
    }
  }
  __syncthreads();

  for (int head = 0; head < 6; ++head) {
    f4v acc[4][3];
#pragma unroll
    for (int mi = 0; mi < 4; ++mi)
#pragma unroll
      for (int nf = 0; nf < 3; ++nf) acc[mi][nf] = (f4v){0.f, 0.f, 0.f, 0.f};
    const int n0 = wid * 64;
    const short* wb = w1p + (size_t)(head * 4 + wid) * (4 * 8 * 64 * 8);
    s8v aWa[4], aWb[4];
#pragma unroll
    for (int mi = 0; mi < 4; ++mi)
      aWa[mi] = *((const s8v*)(wb + ((mi * 8 + 0) * 64 + lane) * 8));
#pragma unroll
    for (int kk = 0; kk < 8; ++kk) {
      s8v (&cur)[4] = (kk & 1) ? aWb : aWa;
      s8v (&nxt)[4] = (kk & 1) ? aWa : aWb;
      if (kk < 7) {
#pragma unroll
        for (int mi = 0; mi < 4; ++mi)
          nxt[mi] = *((const s8v*)(wb + ((mi * 8 + kk + 1) * 64 + lane) * 8));
      }
      s8v bP[3];
#pragma unroll
      for (int nf = 0; nf < 3; ++nf)
        bP[nf] = *((const s8v*)&sA[swz(nf * 16 + l15, kk * 32 + lg * 8)]);
#pragma unroll
      for (int mi = 0; mi < 4; ++mi)
#pragma unroll
        for (int nf = 0; nf < 3; ++nf)
          acc[mi][nf] = __builtin_amdgcn_mfma_f32_16x16x32_bf16(cur[mi], bP[nf], acc[mi][nf], 0, 0, 0);
    }
    // bn + relu -> sH. D: row = out-ch = n0+mi*16+lg*4+r, col = pixel = nf*16+l15.
#pragma unroll
    for (int mi = 0; mi < 4; ++mi) {
      int o4 = n0 + mi * 16 + lg * 4;      // 4 consecutive out-channels
      f4v s4 = *((const f4v*)(g1 + head * 256 + o4));
      f4v c4 = *((const f4v*)(b1 + head * 256 + o4));
#pragma unroll
      for (int nf = 0; nf < 3; ++nf) {
        int pix = nf * 16 + l15;
        s4v pk;
#pragma unroll
        for (int r = 0; r < 4; ++r)
          pk[r] = f2bf(fmaxf(acc[mi][nf][r] * (s4[r] * RSQEPS) + c4[r], 0.f));
        *((s4v*)&sH[swz(pix, o4)]) = pk;   // one ds_write_b64
      }
    }
    __syncthreads();
    if (wid < 3) {  // GEMM2 (transposed): wave w owns pixel-frag w
      f4v a20 = {0.f, 0.f, 0.f, 0.f}, a21 = {0.f, 0.f, 0.f, 0.f};
#pragma unroll
      for (int kk = 0; kk < 8; ++kk) {
        s8v bH = *((const s8v*)&sH[swz(wid * 16 + l15, kk * 32 + lg * 8)]);
        s8v w20 = *((const s8v*)(w2p + ((size_t)(((head * 2 + 0) * 8 + kk) * 64 + lane)) * 8));
        s8v w21 = *((const s8v*)(w2p + ((size_t)(((head * 2 + 1) * 8 + kk) * 64 + lane)) * 8));
        a20 = __builtin_amdgcn_mfma_f32_16x16x32_bf16(w20, bH, a20, 0, 0, 0);
        a21 = __builtin_amdgcn_mfma_f32_16x16x32_bf16(w21, bH, a21, 0, 0, 0);
      }
      // D: row = out2-ch = mf*16+lg*4+r (valid <20), col = pixel = wid*16+l15
#pragma unroll
      for (int mf = 0; mf < 2; ++mf) {
        int ch4 = mf * 16 + lg * 4;
        if (ch4 < 20) {                    // mf=1: only lg==0 (ch 16..19)
          f4v s4 = *((const f4v*)(g2 + head * 20 + ch4));
          f4v c4 = *((const f4v*)(b2 + head * 20 + ch4));
          f4v& aa = mf ? a21 : a20;
#pragma unroll
          for (int r = 0; r < 4; ++r) {
            float v = fmaxf(aa[r] * (s4[r] * RSQEPS) + c4[r], 0.f);
            ctx[(size_t)(head * 20 + ch4 + r) * P_TOT + p0 + wid * 16 + l15] = f2bf(v);
          }
        }
      }
    }
    __syncthreads();
  }
}

// ---------------- K2: att_raw / att_soft / ctx_att, one head per block.y ---
__global__ __launch_bounds__(256) void k2_att(
    const short* __restrict__ ctx,
    const float* __restrict__ attw, const float* __restrict__ attb,
    const float* __restrict__ ctxw, const float* __restrict__ ctxb,
    float* __restrict__ ws_att, float* __restrict__ out) {
  int p = blockIdx.x * 256 + threadIdx.x;
  const int i = blockIdx.y;
  int n = p / 3600, hw = p % 3600;
  const int att_off[6] = {0, 2, 5, 8, 11, 14};
  float fd[10], c0[10];
#pragma unroll
  for (int c = 0; c < 10; ++c) {
    c0[c] = bf2f(ctx[(size_t)(i * 20 + c) * P_TOT + p]);
    fd[c] = bf2f(ctx[(size_t)(i * 20 + 10 + c) * P_TOT + p]);
  }
  const int ci = (i == 0 || i == 5) ? 2 : 3;
  float a[3];
#pragma unroll
  for (int j = 0; j < 3; ++j) {
    if (j < ci) {
      float s = attb[i * 3 + j];
#pragma unroll
      for (int c = 0; c < 10; ++c) s += attw[(i * 3 + j) * 10 + c] * fd[c];
      a[j] = s;
      out[O4 + ((size_t)n * 16 + att_off[i] + j) * 3600 + hw] = s;
    }
  }
  float mx = fmaxf(a[0], a[1]);
  if (ci == 3) mx = fmaxf(mx, a[2]);
  float se = 0.f;
#pragma unroll
  for (int j = 0; j < 3; ++j)
    if (j < ci) { a[j] = __expf(a[j] - mx); se += a[j]; }
  float inv = 1.f / se;
#pragma unroll
  for (int j = 0; j < 3; ++j)
    if (j < ci) ws_att[(size_t)(i * 3 + j) * P_TOT + p] = a[j] * inv;
  float o0 = ctxb[i * 2 + 0];
  float o1 = ctxb[i * 2 + 1];
#pragma unroll
  for (int c = 0; c < 10; ++c) {
    o0 += ctxw[(i * 2 + 0) * 10 + c] * c0[c];
    o1 += ctxw[(i * 2 + 1) * 10 + c] * fd[c];
  }
  out[O5 + ((size_t)n * 12 + i * 2 + 0) * 3600 + hw] = o0;
  out[O5 + ((size_t)n * 12 + i * 2 + 1) * 3600 + hw] = o1;
}

// ---------------- K3: pu/pl maps + softmax gates (split by block.y) --------
__global__ __launch_bounds__(256) void k3_gates(
    const float* __restrict__ xh0, const float* __restrict__ xh1,
    const float* __restrict__ duw, const float* __restrict__ dub,
    const float* __restrict__ dlw, const float* __restrict__ dlb,
    float* __restrict__ ws_pu, float* __restrict__ ws_pl, float* __restrict__ out) {
  int p = blockIdx.x * 256 + threadIdx.x;
  int n = p / 3600, hw = p % 3600;
  if (blockIdx.y == 0) {
    float h[10];
#pragma unroll
    for (int c = 0; c < 10; ++c) h[c] = xh0[((size_t)n * 10 + c) * 3600 + hw];
    float a[5];
#pragma unroll
    for (int j = 0; j < 5; ++j) {
      float s = dub[j];
#pragma unroll
      for (int c = 0; c < 10; ++c) s += duw[j * 10 + c] * h[c];
      a[j] = s;
      out[O2 + ((size_t)n * 5 + j) * 3600 + hw] = s;
    }
    float mx = a[0];
#pragma unroll
    for (int j = 1; j < 5; ++j) mx = fmaxf(mx, a[j]);
    float se = 0.f;
#pragma unroll
    for (int j = 0; j < 5; ++j) { a[j] = __expf(a[j] - mx); se += a[j]; }
    float inv = 1.f / se;
#pragma unroll
    for (int j = 0; j < 5; ++j) ws_pu[(size_t)j * P_TOT + p] = a[j] * inv;
  } else {
    float h[10];
#pragma unroll
    for (int c = 0; c < 10; ++c) h[c] = xh1[((size_t)n * 10 + c) * 3600 + hw];
    float b3[3];
#pragma unroll
    for (int j = 0; j < 3; ++j) {
      float s = dlb[j];
#pragma unroll
      for (int c = 0; c < 10; ++c) s += dlw[j * 10 + c] * h[c];
      b3[j] = s;
      out[O3 + ((size_t)n * 3 + j) * 3600 + hw] = s;
    }
    float mx = fmaxf(fmaxf(b3[0], b3[1]), b3[2]);
    float se = 0.f;
#pragma unroll
    for (int j = 0; j < 3; ++j) { b3[j] = __expf(b3[j] - mx); se += b3[j]; }
    float inv = 1.f / se;
#pragma unroll
    for (int j = 0; j < 3; ++j) ws_pl[(size_t)j * P_TOT + p] = b3[j] * inv;
  }
}

// ---------------- K4a/K4b: dual-pixel, SPLIT to keep live-set < spill ------
// Round-12 merged dual-pixel spilled (VGPR 256). Split: k4a (decoder+edges ->
// ws_msg) and k4b (GRU) each hold only ~100 live f32. Every LDS weight row
// feeds 2 pixels -> DS instruction count halves (the round-11 DS bottleneck).
static __device__ const int INC_N[6] = {1, 2, 2, 2, 2, 1};
static __device__ const int INC_U[6][2] = {{1, 0}, {0, 2}, {1, 3}, {2, 4}, {3, 5}, {4, 0}};
static __device__ const int INC_K[6][2] = {{1, 0}, {1, 1}, {2, 1}, {2, 1}, {2, 1}, {2, 0}};

// k4a LDS (floats): 0: c1w[3][400] | 1200: c1s[3][20] | 1260: c1b[3][20]
// | 1320: c2w[3][200] | 1920: c2s[3][10] | 1950: c2b[3][10]  (1980 total)
template <bool ACCUM>
__device__ __forceinline__ void block2_l2(
    const float* __restrict__ w1, const float* __restrict__ s1, const float* __restrict__ b1,
    const float* __restrict__ w2, const float* __restrict__ s2, const float* __restrict__ b2,
    const float* __restrict__ inaA, const float* __restrict__ inbA,
    const float* __restrict__ inaB, const float* __restrict__ inbB,
    float* __restrict__ outA, float* __restrict__ outB) {
  float hA[20], hB[20];
#pragma unroll
  for (int o = 0; o < 20; ++o) {
    float aA = 0.f, aB = 0.f;
#pragma unroll
    for (int c = 0; c < 10; ++c) {
      float wlo = w1[o * 20 + c], whi = w1[o * 20 + 10 + c];
      aA += wlo * inaA[c] + whi * inbA[c];
      aB += wlo * inaB[c] + whi * inbB[c];
    }
    float ss = s1[o], bb = b1[o];
    hA[o] = fmaxf(aA * ss + bb, 0.f);
    hB[o] = fmaxf(aB * ss + bb, 0.f);
    if ((o & 3) == 3) fence();
  }
#pragma unroll
  for (int o = 0; o < 10; ++o) {
    float aA = 0.f, aB = 0.f;
#pragma unroll
    for (int c = 0; c < 20; ++c) {
      float w = w2[o * 20 + c];
      aA += w * hA[c];
      aB += w * hB[c];
    }
    float ss = s2[o], bb = b2[o];
    float vA = fmaxf(aA * ss + bb, 0.f);
    float vB = fmaxf(aB * ss + bb, 0.f);
    if (ACCUM) { outA[o] += vA; outB[o] += vB; }
    else       { outA[o] = vA;  outB[o] = vB; }
    if ((o & 3) == 3) fence();
  }
  fence();
}

__global__ __launch_bounds__(256) void k4a_msg(
    const float* __restrict__ xh0, const float* __restrict__ xh1,
    const float* __restrict__ xp0, const float* __restrict__ xp1,
    const float* __restrict__ xp2, const float* __restrict__ xp3,
    const float* __restrict__ xp4, const float* __restrict__ xp5,
    const float* __restrict__ ws_pu, const float* __restrict__ ws_pl,
    const float* __restrict__ ws_att, const short* __restrict__ ctx,
    const float* __restrict__ c1wg, const float* __restrict__ c1gg, const float* __restrict__ c1bg,
    const float* __restrict__ c2wg, const float* __restrict__ c2gg, const float* __restrict__ c2bg,
    float* __restrict__ ws_msg) {
  __shared__ float W[1980];
  const int t = threadIdx.x;
  const int node = blockIdx.y;
  for (int u = t; u < 1980; u += 256) {
    float v;
    if (u < 1200) v = c1wg[u];
    else if (u < 1260) v = c1gg[u - 1200] * RSQEPS;
    else if (u < 1320) v = c1bg[u - 1260];
    else if (u < 1920) v = c2wg[u - 1320];
    else if (u < 1950) v = c2gg[u - 1920] * RSQEPS;
    else v = c2bg[u - 1950];
    W[u] = v;
  }
  __syncthreads();
  const int sdec = (node < 4) ? 0 : 1;
  const int pA = blockIdx.x * 512 + t;          // pA <= 57599 always
  const bool vB = pA + 256 < P_TOT;
  const int pB = vB ? pA + 256 : P_TOT - 1;     // clamp loads; stores guarded
  const int nA = pA / 3600, hwA = pA % 3600;
  const int nB = pB / 3600, hwB = pB % 3600;
  const float* xhp = (node < 4) ? xh0 : xh1;
  const float* xpl = node == 0 ? xp0 : node == 1 ? xp1 : node == 2 ? xp2
                   : node == 3 ? xp3 : node == 4 ? xp4 : xp5;
  float xpiA[10], xpiB[10];
#pragma unroll
  for (int c = 0; c < 10; ++c) {
    xpiA[c] = xpl[((size_t)nA * 10 + c) * 3600 + hwA];
    xpiB[c] = xpl[((size_t)nB * 10 + c) * 3600 + hwB];
  }
  const float* gatep = (node < 4) ? ws_pu : ws_pl;
  const int gidx = (node < 4) ? node + 1 : node - 3;
  float attgA = gatep[(size_t)gidx * P_TOT + pA];
  float attgB = gatep[(size_t)gidx * P_TOT + pB];
  float gatedA[10], gatedB[10], msgA[10], msgB[10];
#pragma unroll
  for (int c = 0; c < 10; ++c) {
    gatedA[c] = xhp[((size_t)nA * 10 + c) * 3600 + hwA] * attgA;
    gatedB[c] = xhp[((size_t)nB * 10 + c) * 3600 + hwB] * attgB;
  }
  fence();
  block2_l2<false>(W + sdec * 400, W + 1200 + sdec * 20, W + 1260 + sdec * 20,
                   W + 1320 + sdec * 200, W + 1920 + sdec * 10, W + 1950 + sdec * 10,
                   gatedA, xpiA, gatedB, xpiB, msgA, msgB);
  const int ne = INC_N[node];
#pragma unroll 1
  for (int e = 0; e < ne; ++e) {
    int uu = INC_U[node][e], kk = INC_K[node][e];
    float avA = ws_att[(size_t)(uu * 3 + kk) * P_TOT + pA];
    float avB = ws_att[(size_t)(uu * 3 + kk) * P_TOT + pB];
#pragma unroll
    for (int c = 0; c < 10; ++c) {
      gatedA[c] = avA * bf2f(ctx[(size_t)(uu * 20 + 10 + c) * P_TOT + pA]);
      gatedB[c] = avB * bf2f(ctx[(size_t)(uu * 20 + 10 + c) * P_TOT + pB]);
    }
    fence();
    block2_l2<true>(W + 800, W + 1240, W + 1300, W + 1720, W + 1940, W + 1970,
                    gatedA, xpiA, gatedB, xpiB, msgA, msgB);
  }
#pragma unroll
  for (int c = 0; c < 10; ++c) {
    ws_msg[(size_t)(node * 10 + c) * P_TOT + pA] = msgA[c];
    if (vB) ws_msg[(size_t)(node * 10 + c) * P_TOT + pB] = msgB[c];
  }
}

// k4b LDS (floats): 0: gw[400] | 400: gb[20] | 420: cw[200] | 620: cb[10]
__global__ __launch_bounds__(256) void k4b_gru(
    const float* __restrict__ xp0, const float* __restrict__ xp1,
    const float* __restrict__ xp2, const float* __restrict__ xp3,
    const float* __restrict__ xp4, const float* __restrict__ xp5,
    const float* __restrict__ ws_msg,
    const float* __restrict__ gwg, const float* __restrict__ gbg,
    const float* __restrict__ cwg, const float* __restrict__ cbg,
    float* __restrict__ out) {
  __shared__ float W[630];
  const int t = threadIdx.x;
  const int node = blockIdx.y;
  for (int u = t; u < 630; u += 256) {
    float v;
    if (u < 400) v = gwg[node * 400 + u];
    else if (u < 420) v = gbg[node * 20 + (u - 400)];
    else if (u < 620) v = cwg[node * 200 + (u - 420)];
    else v = cbg[node * 10 + (u - 620)];
    W[u] = v;
  }
  __syncthreads();
  const int pA = blockIdx.x * 512 + t;
  const bool vB = pA + 256 < P_TOT;
  const int pB = vB ? pA + 256 : P_TOT - 1;
  const int nA = pA / 3600, hwA = pA % 3600;
  const int nB = pB / 3600, hwB = pB % 3600;
  const float* xpl = node == 0 ? xp0 : node == 1 ? xp1 : node == 2 ? xp2
                   : node == 3 ? xp3 : node == 4 ? xp4 : xp5;
  float xpiA[10], xpiB[10], msgA[10], msgB[10];
#pragma unroll
  for (int c = 0; c < 10; ++c) {
    xpiA[c] = xpl[((size_t)nA * 10 + c) * 3600 + hwA];
    xpiB[c] = xpl[((size_t)nB * 10 + c) * 3600 + hwB];
    msgA[c] = ws_msg[(size_t)(node * 10 + c) * P_TOT + pA];
    msgB[c] = ws_msg[(size_t)(node * 10 + c) * P_TOT + pB];
  }
  fence();
  float g20A[20], g20B[20];
#pragma unroll
  for (int o = 0; o < 20; ++o) {
    float aA = W[400 + o], aB = aA;
#pragma unroll
    for (int c = 0; c < 10; ++c) {
      float wlo = W[o * 20 + c], whi = W[o * 20 + 10 + c];
      aA += wlo * msgA[c] + whi * xpiA[c];
      aB += wlo * msgB[c] + whi * xpiB[c];
    }
    g20A[o] = aA; g20B[o] = aB;
    if ((o & 3) == 3) fence();
  }
  float rhA[10], rhB[10];
#pragma unroll
  for (int c = 0; c < 10; ++c) {
    rhA[c] = xpiA[c] / (1.f + __expf(-g20A[c]));
    rhB[c] = xpiB[c] / (1.f + __expf(-g20B[c]));
  }
#pragma unroll
  for (int o = 0; o < 10; ++o) {
    float aA = W[620 + o], aB = aA;
#pragma unroll
    for (int c = 0; c < 10; ++c) {
      float wlo = W[420 + o * 20 + c], whi = W[420 + o * 20 + 10 + c];
      aA += wlo * msgA[c] + whi * rhA[c];
      aB += wlo * msgB[c] + whi * rhB[c];
    }
    // tanh(x) = 1 - 2/(exp(2x)+1), inline, saturating
    float cdA = 1.f - 2.f / (__expf(2.f * aA) + 1.f);
    float cdB = 1.f - 2.f / (__expf(2.f * aB) + 1.f);
    float zA = 1.f / (1.f + __expf(-g20A[10 + o]));
    float zB = 1.f / (1.f + __expf(-g20B[10 + o]));
    out[((size_t)nA * 60 + node * 10 + o) * 3600 + hwA] = (1.f - zA) * xpiA[o] + zA * cdA;
    if (vB)
      out[((size_t)nB * 60 + node * 10 + o) * 3600 + hwB] = (1.f - zB) * xpiB[o] + zB * cdB;
    if ((o & 3) == 3) fence();
  }
}

// ---------------- launcher -------------------------------------------------
extern "C" void kernel_launch(void* const* d_in, const int* in_sizes, int n_in,
                              void* d_out, int out_size, void* d_ws, size_t ws_size,
                              hipStream_t stream) {
  const float* xh0 = (const float*)d_in[1];
  const float* xh1 = (const float*)d_in[2];
  const float* xp0 = (const float*)d_in[3];
  const float* xp1 = (const float*)d_in[4];
  const float* xp2 = (const float*)d_in[5];
  const float* xp3 = (const float*)d_in[6];
  const float* xp4 = (const float*)d_in[7];
  const float* xp5 = (const float*)d_in[8];
  const float* xp  = (const float*)d_in[9];
  const float* p1w = (const float*)d_in[10];
  const float* p1g = (const float*)d_in[11];
  const float* p1b = (const float*)d_in[12];
  const float* p2w = (const float*)d_in[13];
  const float* p2g = (const float*)d_in[14];
  const float* p2b = (const float*)d_in[15];
  const float* attw = (const float*)d_in[16];
  const float* attb = (const float*)d_in[17];
  const float* ctxw = (const float*)d_in[18];
  const float* ctxb = (const float*)d_in[19];
  const float* duw = (const float*)d_in[20];
  const float* dub = (const float*)d_in[21];
  const float* dlw = (const float*)d_in[22];
  const float* dlb = (const float*)d_in[23];
  const float* c1w = (const float*)d_in[24];
  const float* c1g = (const float*)d_in[25];
  const float* c1b = (const float*)d_in[26];
  const float* c2w = (const float*)d_in[27];
  const float* c2g = (const float*)d_in[28];
  const float* c2b = (const float*)d_in[29];
  const float* gw  = (const float*)d_in[30];
  const float* gb  = (const float*)d_in[31];
  const float* cw  = (const float*)d_in[32];
  const float* cb  = (const float*)d_in[33];

  // Workspace layout (bytes) — total 34,523,136 B (~33 MB):
  char* wsb = (char*)d_ws;
  short* w1p   = (short*)(wsb);              //    786,432 B
  short* w2p   = (short*)(wsb + 786432);     //     98,304 B
  short* ctxb2 = (short*)(wsb + 884736);     // 13,824,000 B (bf16 ctx [120][57600])
  float* ws_att = (float*)(wsb + 14708736);  //  4,147,200 B
  float* ws_pu  = (float*)(wsb + 18855936);  //  1,152,000 B
  float* ws_pl  = (float*)(wsb + 20007936);  //    691,200 B
  float* ws_msg = (float*)(wsb + 20699136);  // 13,824,000 B (f32 msg [60][57600])
  float* out = (float*)d_out;

  k0_prep<<<216, 256, 0, stream>>>(p1w, p2w, w1p, w2p);
  k1_proj<<<1200, 256, 0, stream>>>(xp, w1p, p1g, p1b, w2p, p2g, p2b, ctxb2);
  k2_att<<<dim3(225, 6), 256, 0, stream>>>(ctxb2, attw, attb, ctxw, ctxb, ws_att, out);
  k3_gates<<<dim3(225, 2), 256, 0, stream>>>(xh0, xh1, duw, dub, dlw, dlb, ws_pu, ws_pl, out);
  k4a_msg<<<dim3(113, 6), 256, 0, stream>>>(xh0, xh1, xp0, xp1, xp2, xp3, xp4, xp5,
      ws_pu, ws_pl, ws_att, ctxb2, c1w, c1g, c1b, c2w, c2g, c2b, ws_msg);
  k4b_gru<<<dim3(113, 6), 256, 0, stream>>>(xp0, xp1, xp2, xp3, xp4, xp5,
      ws_msg, gw, gb, cw, cb, out);
}